// Round 3
// baseline (2585.663 us; speedup 1.0000x reference)
//
#include <hip/hip_runtime.h>

#define NN 512
#define BSZ 64
#define TTOT 200
#define NSTEP 199
#define DD 32

typedef __attribute__((ext_vector_type(8))) short bf16x8;
typedef __attribute__((ext_vector_type(4))) float f32x4;
typedef __attribute__((ext_vector_type(4))) unsigned int u32x4;

__device__ __forceinline__ float bf2f(unsigned short u) {
  union { unsigned int i; float f; } v; v.i = ((unsigned int)u) << 16; return v.f;
}
__device__ __forceinline__ unsigned short f2bf(float f) {  // RNE
  unsigned int b = __float_as_uint(f);
  return (unsigned short)((b + 0x7fffu + ((b >> 16) & 1u)) >> 16);
}
// truncation-pack two f32 -> (bf(hi)<<16)|bf(lo) via one v_perm_b32
__device__ __forceinline__ unsigned int pk_trunc(float hi, float lo) {
  return __builtin_amdgcn_perm(__float_as_uint(hi), __float_as_uint(lo), 0x07060302u);
}

// ---------------------------------------------------------------------------
// Transpose+convert: A1 (f32 row-major [b][r][c]) -> A1T (bf16 [b][c][r]).
// 64x64 tiles; LDS holds u32 r-pairs; all LDS access verified 2-way (free).
// ---------------------------------------------------------------------------
__global__ __launch_bounds__(256) void transpose_kernel(
    const float* __restrict__ A1, unsigned short* __restrict__ A1T) {
  const int b = blockIdx.z, rt = blockIdx.y * 64, ct = blockIdx.x * 64;
  const int t = threadIdx.x;
  __shared__ unsigned int tl[64][33];  // [c][r_pair]

  {
    const int rp = t >> 3, cs = (t & 7) * 8;
    const float* p0 = A1 + (size_t)b * NN * NN + (size_t)(rt + 2 * rp) * NN + ct + cs;
    f32x4 a0 = *(const f32x4*)p0, a1 = *(const f32x4*)(p0 + 4);
    f32x4 b0 = *(const f32x4*)(p0 + NN), b1 = *(const f32x4*)(p0 + NN + 4);
#pragma unroll
    for (int j = 0; j < 4; ++j) {
      tl[cs + j][rp] = pk_trunc(b0[j], a0[j]);
      tl[cs + 4 + j][rp] = pk_trunc(b1[j], a1[j]);
    }
  }
  __syncthreads();
  {
    const int c = t >> 2, rps = (t & 3) * 8;
    unsigned int v[8];
#pragma unroll
    for (int j = 0; j < 8; ++j) v[j] = tl[c][rps + j];
    unsigned int* dst = (unsigned int*)(A1T + (size_t)b * NN * NN +
                                        (size_t)(ct + c) * NN + rt) + rps;
    *(u32x4*)dst = u32x4{v[0], v[1], v[2], v[3]};
    *(u32x4*)(dst + 4) = u32x4{v[4], v[5], v[6], v[7]};
  }
}

// ---------------------------------------------------------------------------
// Fast GEMM 1: A2[b] = A1[b] @ A1[b] (bf16 out). a-frags: f32 direct +
// trunc-pack; b-frags: one contiguous 16B load from A1T.
// ---------------------------------------------------------------------------
__global__ __launch_bounds__(256) void gemm_a2_fast(
    const float* __restrict__ A1, const unsigned short* __restrict__ A1T,
    unsigned short* __restrict__ A2) {
  const int b = blockIdx.z, tm = blockIdx.y, tn = blockIdx.x;
  const int tid = threadIdx.x, lane = tid & 63, w = tid >> 6;
  const int q = lane >> 4, ln = lane & 15;
  const size_t Ao = (size_t)b * NN * NN;
  f32x4 zero = {0.f, 0.f, 0.f, 0.f};
  f32x4 acc[4] = {zero, zero, zero, zero};
  const float* ap = A1 + Ao + (size_t)(tm * 64 + w * 16 + ln) * NN + q * 8;
  const unsigned short* bt = A1T + Ao;
  for (int k0 = 0; k0 < NN; k0 += 32) {
    f32x4 x0 = *(const f32x4*)(ap + k0);
    f32x4 x1 = *(const f32x4*)(ap + k0 + 4);
    union { bf16x8 v; unsigned int u[4]; } af;
    af.u[0] = pk_trunc(x0[1], x0[0]);
    af.u[1] = pk_trunc(x0[3], x0[2]);
    af.u[2] = pk_trunc(x1[1], x1[0]);
    af.u[3] = pk_trunc(x1[3], x1[2]);
#pragma unroll
    for (int i = 0; i < 4; ++i) {
      bf16x8 bv = *(const bf16x8*)(bt + (size_t)(tn * 64 + i * 16 + ln) * NN + k0 + q * 8);
      acc[i] = __builtin_amdgcn_mfma_f32_16x16x32_bf16(af.v, bv, acc[i], 0, 0, 0);
    }
  }
  unsigned short* Cb = A2 + Ao;
#pragma unroll
  for (int i = 0; i < 4; ++i) {
    int col = tn * 64 + i * 16 + ln;
#pragma unroll
    for (int r = 0; r < 4; ++r) {
      int row = tm * 64 + w * 16 + q * 4 + r;
      Cb[(size_t)row * NN + col] = f2bf(acc[i][r]);
    }
  }
}

// ---------------------------------------------------------------------------
// Fast GEMM 2: A3 = A2 @ A1; epilogue M = c1*A1 + c2*A2 + c3*A3 scattered into
// B-fragment-blocked layout (frag=(col>>4)*16+(row>>5); l2=((row>>3)&3)*16+
// (col&15); elem=row&7) so the scan's b_frag is one 16B load.
// ---------------------------------------------------------------------------
__global__ __launch_bounds__(256) void gemm_m_fast(
    const float* __restrict__ A1, const unsigned short* __restrict__ A1T,
    const unsigned short* __restrict__ A2, unsigned short* __restrict__ Mfrag) {
  const int b = blockIdx.z, tm = blockIdx.y, tn = blockIdx.x;
  const int tid = threadIdx.x, lane = tid & 63, w = tid >> 6;
  const int q = lane >> 4, ln = lane & 15;
  const size_t Ao = (size_t)b * NN * NN;
  const unsigned short* A2b = A2 + Ao;
  f32x4 zero = {0.f, 0.f, 0.f, 0.f};
  f32x4 acc[4] = {zero, zero, zero, zero};
  const unsigned short* ap = A2b + (size_t)(tm * 64 + w * 16 + ln) * NN + q * 8;
  const unsigned short* bt = A1T + Ao;
  for (int k0 = 0; k0 < NN; k0 += 32) {
    bf16x8 af = *(const bf16x8*)(ap + k0);
#pragma unroll
    for (int i = 0; i < 4; ++i) {
      bf16x8 bv = *(const bf16x8*)(bt + (size_t)(tn * 64 + i * 16 + ln) * NN + k0 + q * 8);
      acc[i] = __builtin_amdgcn_mfma_f32_16x16x32_bf16(af, bv, acc[i], 0, 0, 0);
    }
  }
  const float c1 = 1.f / (3.f * 512.f * 512.f);
  const float c2 = c1 / 512.f;
  const float c3 = c2 / 512.f;
  unsigned short* Mb = Mfrag + Ao;
#pragma unroll
  for (int i = 0; i < 4; ++i) {
    int col = tn * 64 + i * 16 + ln;
#pragma unroll
    for (int r = 0; r < 4; ++r) {
      int row = tm * 64 + w * 16 + q * 4 + r;
      float mval = c1 * A1[Ao + (size_t)row * NN + col] +
                   c2 * bf2f(A2b[(size_t)row * NN + col]) + c3 * acc[i][r];
      int nt = col >> 4, cch = row >> 5;
      int l2 = ((row >> 3) & 3) * 16 + (col & 15);
      int jj = row & 7;
      Mb[(size_t)((nt * 16 + cch) * 512) + l2 * 8 + jj] = f2bf(mval);
    }
  }
}

// ---------------------------------------------------------------------------
// Slow-path GEMMs (no A1T workspace): round-2 proven versions, f32 input.
// ---------------------------------------------------------------------------
__global__ __launch_bounds__(256) void gemm_a2_slow(
    const float* __restrict__ A1, unsigned short* __restrict__ A2) {
  const int b = blockIdx.z, tm = blockIdx.y, tn = blockIdx.x;
  const int tid = threadIdx.x, lane = tid & 63, w = tid >> 6;
  const int q = lane >> 4, ln = lane & 15;
  const size_t Ao = (size_t)b * NN * NN;
  f32x4 zero = {0.f, 0.f, 0.f, 0.f};
  f32x4 acc[4] = {zero, zero, zero, zero};
  const float* ap = A1 + Ao + (size_t)(tm * 64 + w * 16 + ln) * NN + q * 8;
  for (int k0 = 0; k0 < NN; k0 += 32) {
    f32x4 x0 = *(const f32x4*)(ap + k0);
    f32x4 x1 = *(const f32x4*)(ap + k0 + 4);
    union { bf16x8 v; unsigned int u[4]; } af;
    af.u[0] = pk_trunc(x0[1], x0[0]);
    af.u[1] = pk_trunc(x0[3], x0[2]);
    af.u[2] = pk_trunc(x1[1], x1[0]);
    af.u[3] = pk_trunc(x1[3], x1[2]);
#pragma unroll
    for (int i = 0; i < 4; ++i) {
      bf16x8 bv;
#pragma unroll
      for (int j = 0; j < 8; ++j)
        bv[j] = (short)f2bf(A1[Ao + (size_t)(k0 + q * 8 + j) * NN + tn * 64 + i * 16 + ln]);
      acc[i] = __builtin_amdgcn_mfma_f32_16x16x32_bf16(af.v, bv, acc[i], 0, 0, 0);
    }
  }
  unsigned short* Cb = A2 + Ao;
#pragma unroll
  for (int i = 0; i < 4; ++i) {
    int col = tn * 64 + i * 16 + ln;
#pragma unroll
    for (int r = 0; r < 4; ++r) {
      int row = tm * 64 + w * 16 + q * 4 + r;
      Cb[(size_t)row * NN + col] = f2bf(acc[i][r]);
    }
  }
}

__global__ __launch_bounds__(256) void gemm_m_slow(
    const float* __restrict__ A1, const unsigned short* __restrict__ A2,
    unsigned short* __restrict__ Mfrag) {
  const int b = blockIdx.z, tm = blockIdx.y, tn = blockIdx.x;
  const int tid = threadIdx.x, lane = tid & 63, w = tid >> 6;
  const int q = lane >> 4, ln = lane & 15;
  const size_t Ao = (size_t)b * NN * NN;
  const unsigned short* A2b = A2 + Ao;
  f32x4 zero = {0.f, 0.f, 0.f, 0.f};
  f32x4 acc[4] = {zero, zero, zero, zero};
  const unsigned short* ap = A2b + (size_t)(tm * 64 + w * 16 + ln) * NN + q * 8;
  for (int k0 = 0; k0 < NN; k0 += 32) {
    bf16x8 af = *(const bf16x8*)(ap + k0);
#pragma unroll
    for (int i = 0; i < 4; ++i) {
      bf16x8 bv;
#pragma unroll
      for (int j = 0; j < 8; ++j)
        bv[j] = (short)f2bf(A1[Ao + (size_t)(k0 + q * 8 + j) * NN + tn * 64 + i * 16 + ln]);
      acc[i] = __builtin_amdgcn_mfma_f32_16x16x32_bf16(af, bv, acc[i], 0, 0, 0);
    }
  }
  const float c1 = 1.f / (3.f * 512.f * 512.f);
  const float c2 = c1 / 512.f;
  const float c3 = c2 / 512.f;
  unsigned short* Mb = Mfrag + Ao;
#pragma unroll
  for (int i = 0; i < 4; ++i) {
    int col = tn * 64 + i * 16 + ln;
#pragma unroll
    for (int r = 0; r < 4; ++r) {
      int row = tm * 64 + w * 16 + q * 4 + r;
      float mval = c1 * A1[Ao + (size_t)row * NN + col] +
                   c2 * bf2f(A2b[(size_t)row * NN + col]) + c3 * acc[i][r];
      int nt = col >> 4, cch = row >> 5;
      int l2 = ((row >> 3) & 3) * 16 + (col & 15);
      int jj = row & 7;
      Mb[(size_t)((nt * 16 + cch) * 512) + l2 * 8 + jj] = f2bf(mval);
    }
  }
}

// ---------------------------------------------------------------------------
// Scan: 64 blocks x 512 threads, 199 steps. M is STEP-INVARIANT -> preloaded
// into 256 VGPRs/thread (64 bf16x8 frags). Matvec = 64 MFMA/wave/step from
// registers; a-frags are 16 ds_read_b128 broadcasts of lpb. MLP runs on all
// 64 lanes of wave 0 with split chains.
// ---------------------------------------------------------------------------
__global__ __launch_bounds__(512) void scan_kernel(
    const int* __restrict__ skills, const int* __restrict__ times,
    const float* __restrict__ labels, const float* __restrict__ emb,
    const float* __restrict__ user_b0, const float* __restrict__ user_f0,
    const float* __restrict__ w1g, const float* __restrict__ b1g,
    const float* __restrict__ w2g, const float* __restrict__ b2g,
    const float* __restrict__ wfg, const float* __restrict__ bfg,
    const float* __restrict__ wbg, const float* __restrict__ bbg,
    const unsigned short* __restrict__ Mfrag, float* __restrict__ out) {
  const int b = blockIdx.x;
  const int t = threadIdx.x;
  const int lane = t & 63, w = t >> 6, q = lane >> 4;

  __shared__ float lp[NN];
  __shared__ __align__(16) unsigned short lpb[NN];
  __shared__ float nlf[NN];
  __shared__ float ub[2][DD], uf[2][DD];
  __shared__ float delta_s[NSTEP];
  __shared__ float label_s[NSTEP];
  __shared__ int skill_s[NSTEP];
  __shared__ float hp[16][33];
  __shared__ float w1t[DD * 5 * DD];
  __shared__ float w2t[DD * DD];
  __shared__ float wft[DD * DD], wbt[DD * DD];
  __shared__ float b1s[DD], b2s[DD], bfs[DD], bbs[DD];

  float nrec[DD], nsend[DD];
#pragma unroll
  for (int c = 0; c < DD; ++c) {
    nsend[c] = emb[(size_t)t * (2 * DD) + c];
    nrec[c] = emb[(size_t)t * (2 * DD) + DD + c];
  }
  for (int idx = t; idx < DD * DD * 5; idx += 512) {
    int o = idx / 160, rem = idx % 160;
    w1t[rem * 32 + o] = w1g[idx];
  }
  for (int idx = t; idx < DD * DD; idx += 512) {
    int o = idx >> 5, c = idx & 31;
    w2t[c * 32 + o] = w2g[idx];
    wft[c * 32 + o] = wfg[idx];
    wbt[c * 32 + o] = wbg[idx];
  }
  if (t < DD) {
    b1s[t] = b1g[t]; b2s[t] = b2g[t];
    bfs[t] = bfg[t]; bbs[t] = bbg[t];
    ub[0][t] = user_b0[b * DD + t];
    uf[0][t] = user_f0[b * DD + t];
  }
  for (int i = t; i < NSTEP; i += 512) {
    int dt_ = times[b * TTOT + i + 1] - times[b * TTOT + i];
    if (dt_ < 0) dt_ = -dt_;
    delta_s[i] = __logf((float)dt_ + 1e-6f) * 0.6213349345596119f;  // 1/ln 5
    label_s[i] = labels[b * TTOT + i + 1];
    skill_s[i] = skills[b * TTOT + i + 1];
  }

  // preload step-invariant M fragments into registers (256 VGPRs)
  const unsigned short* Mb = Mfrag + (size_t)b * NN * NN;
  bf16x8 mreg[64];
#pragma unroll
  for (int c = 0; c < 16; ++c)
#pragma unroll
    for (int i = 0; i < 4; ++i)
      mreg[c * 4 + i] = *((const bf16x8*)(Mb + ((size_t)(w * 64 + c) << 9) +
                                          (size_t)i * 8192) + lane);
  __syncthreads();

  {
    float a = 0.f, f = 0.f;
#pragma unroll
    for (int c = 0; c < DD; ++c) {
      a += ub[0][c] * nrec[c];
      f += uf[0][c] * nsend[c];
    }
    lp[t] = a; lpb[t] = f2bf(a); nlf[t] = f;
  }
  __syncthreads();

  int p = 0;
  for (int step = 0; step < NSTEP; ++step) {
    // -------- Phase A (reads old state) --------
    f32x4 zero = {0.f, 0.f, 0.f, 0.f};
    f32x4 acc[4] = {zero, zero, zero, zero};
#pragma unroll
    for (int c = 0; c < 16; ++c) {
      bf16x8 af = *(const bf16x8*)(lpb + c * 32 + q * 8);
#pragma unroll
      for (int i = 0; i < 4; ++i)
        acc[i] = __builtin_amdgcn_mfma_f32_16x16x32_bf16(af, mreg[c * 4 + i],
                                                         acc[i], 0, 0, 0);
    }
    float spatial = (q == 0) ? acc[0][0]
                  : (q == 1) ? acc[1][0]
                  : (q == 2) ? acc[2][0] : acc[3][0];

    float ncb = 0.f, nlfn = 0.f;
#pragma unroll
    for (int c = 0; c < DD; ++c) {
      ncb += ub[p][c] * nrec[c];
      nlfn += uf[p][c] * nsend[c];
    }
    float e = __expf(-delta_s[step] * 0.1f * nlf[t]) * lp[t];
    float cur = 1.f / (1.f + __expf(-(ncb + e + spatial)));

    {  // MLP h partials: all 512 threads
      int o = t & 31, s = t >> 5;
      float lab = label_s[step];
      int sk = skill_s[step];
      float hpart = 0.f;
#pragma unroll
      for (int cc = 0; cc < 2; ++cc) {
        int c = (s << 1) + cc;
        const float* wrow = &w1t[(c * 5) * 32 + o];
        float rs = emb[(size_t)sk * (2 * DD) + c];
        float rr = emb[(size_t)sk * (2 * DD) + DD + c];
        hpart += ub[p][c] * wrow[0] + uf[p][c] * wrow[32] + lab * wrow[64] +
                 rr * wrow[96] + rs * wrow[128];
      }
      hp[s][o] = hpart;
    }
    __syncthreads();

    // -------- Phase B (writes new state) --------
    lp[t] = cur;
    lpb[t] = f2bf(cur);
    nlf[t] = nlfn;
    if (t == skill_s[step]) out[step * BSZ + b] = cur;

    if (w == 0) {  // wave 0, all 64 lanes: split-chain MLP
      int o = lane & 31, half = lane >> 5;
      float part = 0.f;
#pragma unroll
      for (int s = 0; s < 8; ++s) part += hp[half * 8 + s][o];
      float h = b1s[o] + part + __shfl(part, lane ^ 32);
      h = fmaxf(h, 0.f);  // all 64 lanes hold h[o]
      float up = 0.f;
#pragma unroll
      for (int cc = 0; cc < 16; ++cc) {
        int c = half * 16 + cc;
        up += __shfl(h, c) * w2t[c * 32 + o];
      }
      float uu = b2s[o] + up + __shfl(up, lane ^ 32);
      const float* wsel = half ? wbt : wft;
      float aacc = half ? bbs[o] : bfs[o];
#pragma unroll
      for (int c = 0; c < DD; ++c)
        aacc += __shfl(uu, c) * wsel[c * 32 + o];
      float val = 1.f - 2.f / (1.f + __expf(2.f * aacc));
      if (half) ub[p ^ 1][o] = val;  // new_b -> user_b
      else uf[p ^ 1][o] = val;       // new_f -> user_f
    }
    __syncthreads();
    p ^= 1;
  }
}

extern "C" void kernel_launch(void* const* d_in, const int* in_sizes, int n_in,
                              void* d_out, int out_size, void* d_ws, size_t ws_size,
                              hipStream_t stream) {
  (void)in_sizes; (void)n_in; (void)out_size;
  const int* skills = (const int*)d_in[0];
  const int* times = (const int*)d_in[1];
  const float* labels = (const float*)d_in[2];
  const float* adj = (const float*)d_in[3];
  const float* emb = (const float*)d_in[4];

  const size_t mat = (size_t)BSZ * NN * NN;  // elements per bf16 matrix set
  unsigned short* A2 = (unsigned short*)((char*)d_ws + 256);
  unsigned short* Mfrag = A2 + mat;
  size_t need_fast = 256 + 3 * mat * sizeof(unsigned short);

  dim3 gg(8, 8, BSZ), gb(256);
  if (ws_size >= need_fast) {
    unsigned short* A1T = Mfrag + mat;
    transpose_kernel<<<gg, gb, 0, stream>>>(adj, A1T);
    gemm_a2_fast<<<gg, gb, 0, stream>>>(adj, A1T, A2);
    gemm_m_fast<<<gg, gb, 0, stream>>>(adj, A1T, A2, Mfrag);
  } else {
    gemm_a2_slow<<<gg, gb, 0, stream>>>(adj, A2);
    gemm_m_slow<<<gg, gb, 0, stream>>>(adj, A2, Mfrag);
  }
  scan_kernel<<<dim3(BSZ), dim3(512), 0, stream>>>(
      skills, times, labels, emb, (const float*)d_in[5], (const float*)d_in[6],
      (const float*)d_in[7], (const float*)d_in[8], (const float*)d_in[9],
      (const float*)d_in[10], (const float*)d_in[11], (const float*)d_in[12],
      (const float*)d_in[13], (const float*)d_in[14], Mfrag, (float*)d_out);
}

// Round 4
// 899.313 us; speedup vs baseline: 2.8752x; 2.8752x over previous
//
#include <hip/hip_runtime.h>

#define NN 512
#define BSZ 64
#define TTOT 200
#define NSTEP 199
#define DD 32

typedef __attribute__((ext_vector_type(8))) short bf16x8;
typedef __attribute__((ext_vector_type(4))) float f32x4;
typedef __attribute__((ext_vector_type(4))) unsigned int u32x4;

__device__ __forceinline__ float bf2f(unsigned short u) {
  union { unsigned int i; float f; } v; v.i = ((unsigned int)u) << 16; return v.f;
}
__device__ __forceinline__ unsigned short f2bf(float f) {  // RNE
  unsigned int b = __float_as_uint(f);
  return (unsigned short)((b + 0x7fffu + ((b >> 16) & 1u)) >> 16);
}
__device__ __forceinline__ unsigned int pk_trunc(float hi, float lo) {
  return __builtin_amdgcn_perm(__float_as_uint(hi), __float_as_uint(lo), 0x07060302u);
}
// software f32 -> e4m3 (OCP), RNE on normals, sloppy-but-tiny near denormals
__device__ __forceinline__ unsigned char e4m3(float x) {
  float a = fabsf(x);
  unsigned int s = (__float_as_uint(x) >> 24) & 0x80u;
  if (a < 0.01171875f) return (unsigned char)s;  // < 0.75*2^-6 -> 0
  a = fminf(a, 448.0f);
  unsigned int u = __float_as_uint(a);
  unsigned int keep = (u >> 20) & 7u;
  unsigned int rest = u & 0xFFFFFu;
  unsigned int base = (((u >> 23) - 120u) << 3) | keep;
  unsigned int rnd = (rest > 0x80000u) || (rest == 0x80000u && (keep & 1u));
  return (unsigned char)(s | (base + rnd));
}
__device__ __forceinline__ float rlane(float v, int l) {
  return __int_as_float(__builtin_amdgcn_readlane(__float_as_int(v), l));
}

// M8 fragment address for M[row=k][col]:
//   f = (col>>6)*64 + ((col>>4)&3)*16 + (k>>5); lane=((k>>3)&3)*16+(col&15); byte=k&7
__device__ __forceinline__ size_t m8_addr(int k, int col) {
  int f = ((col >> 6) << 6) + (((col >> 4) & 3) << 4) + (k >> 5);
  int ln2 = (((k >> 3) & 3) << 4) + (col & 15);
  return ((size_t)f << 9) + (size_t)ln2 * 8 + (size_t)(k & 7);
}

// ---------------------------------------------------------------------------
// Transpose+convert: A1 (f32 [b][r][c]) -> A1T (bf16 [b][c][r]).
// ---------------------------------------------------------------------------
__global__ __launch_bounds__(256) void transpose_kernel(
    const float* __restrict__ A1, unsigned short* __restrict__ A1T) {
  const int b = blockIdx.x, ct = blockIdx.y * 64, rt = blockIdx.z * 64;
  const int t = threadIdx.x;
  __shared__ unsigned int tl[64][33];
  {
    const int rp = t >> 3, cs = (t & 7) * 8;
    const float* p0 = A1 + (size_t)b * NN * NN + (size_t)(rt + 2 * rp) * NN + ct + cs;
    f32x4 a0 = *(const f32x4*)p0, a1 = *(const f32x4*)(p0 + 4);
    f32x4 b0 = *(const f32x4*)(p0 + NN), b1 = *(const f32x4*)(p0 + NN + 4);
#pragma unroll
    for (int j = 0; j < 4; ++j) {
      tl[cs + j][rp] = pk_trunc(b0[j], a0[j]);
      tl[cs + 4 + j][rp] = pk_trunc(b1[j], a1[j]);
    }
  }
  __syncthreads();
  {
    const int c = t >> 2, rps = (t & 3) * 8;
    unsigned int v[8];
#pragma unroll
    for (int j = 0; j < 8; ++j) v[j] = tl[c][rps + j];
    unsigned int* dst = (unsigned int*)(A1T + (size_t)b * NN * NN +
                                        (size_t)(ct + c) * NN + rt) + rps;
    *(u32x4*)dst = u32x4{v[0], v[1], v[2], v[3]};
    *(u32x4*)(dst + 4) = u32x4{v[4], v[5], v[6], v[7]};
  }
}

// ---------------------------------------------------------------------------
// GEMM 1 (fast): A2[b] = A1[b] @ A1[b], bf16 out.
// ---------------------------------------------------------------------------
__global__ __launch_bounds__(256) void gemm_a2_fast(
    const float* __restrict__ A1, const unsigned short* __restrict__ A1T,
    unsigned short* __restrict__ A2) {
  const int b = blockIdx.x, tn = blockIdx.y, tm = blockIdx.z;
  const int tid = threadIdx.x, lane = tid & 63, w = tid >> 6;
  const int q = lane >> 4, ln = lane & 15;
  const size_t Ao = (size_t)b * NN * NN;
  f32x4 zero = {0.f, 0.f, 0.f, 0.f};
  f32x4 acc[4] = {zero, zero, zero, zero};
  const float* ap = A1 + Ao + (size_t)(tm * 64 + w * 16 + ln) * NN + q * 8;
  const unsigned short* bt = A1T + Ao;
  for (int k0 = 0; k0 < NN; k0 += 32) {
    f32x4 x0 = *(const f32x4*)(ap + k0);
    f32x4 x1 = *(const f32x4*)(ap + k0 + 4);
    union { bf16x8 v; unsigned int u[4]; } af;
    af.u[0] = pk_trunc(x0[1], x0[0]);
    af.u[1] = pk_trunc(x0[3], x0[2]);
    af.u[2] = pk_trunc(x1[1], x1[0]);
    af.u[3] = pk_trunc(x1[3], x1[2]);
#pragma unroll
    for (int i = 0; i < 4; ++i) {
      bf16x8 bv = *(const bf16x8*)(bt + (size_t)(tn * 64 + i * 16 + ln) * NN + k0 + q * 8);
      acc[i] = __builtin_amdgcn_mfma_f32_16x16x32_bf16(af.v, bv, acc[i], 0, 0, 0);
    }
  }
  unsigned short* Cb = A2 + Ao;
#pragma unroll
  for (int i = 0; i < 4; ++i) {
    int col = tn * 64 + i * 16 + ln;
#pragma unroll
    for (int r = 0; r < 4; ++r) {
      int row = tm * 64 + w * 16 + q * 4 + r;
      Cb[(size_t)row * NN + col] = f2bf(acc[i][r]);
    }
  }
}

// ---------------------------------------------------------------------------
// GEMM 2 (fast): A3 = A2 @ A1; epilogue M*2^20 -> e4m3, scattered to frag layout.
// ---------------------------------------------------------------------------
__global__ __launch_bounds__(256) void gemm_m_fast(
    const float* __restrict__ A1, const unsigned short* __restrict__ A1T,
    const unsigned short* __restrict__ A2, unsigned char* __restrict__ M8) {
  const int b = blockIdx.x, tn = blockIdx.y, tm = blockIdx.z;
  const int tid = threadIdx.x, lane = tid & 63, w = tid >> 6;
  const int q = lane >> 4, ln = lane & 15;
  const size_t Ao = (size_t)b * NN * NN;
  const unsigned short* A2b = A2 + Ao;
  f32x4 zero = {0.f, 0.f, 0.f, 0.f};
  f32x4 acc[4] = {zero, zero, zero, zero};
  const unsigned short* ap = A2b + (size_t)(tm * 64 + w * 16 + ln) * NN + q * 8;
  const unsigned short* bt = A1T + Ao;
  for (int k0 = 0; k0 < NN; k0 += 32) {
    bf16x8 af = *(const bf16x8*)(ap + k0);
#pragma unroll
    for (int i = 0; i < 4; ++i) {
      bf16x8 bv = *(const bf16x8*)(bt + (size_t)(tn * 64 + i * 16 + ln) * NN + k0 + q * 8);
      acc[i] = __builtin_amdgcn_mfma_f32_16x16x32_bf16(af, bv, acc[i], 0, 0, 0);
    }
  }
  const float c1 = 1048576.f / (3.f * 512.f * 512.f);  // *2^20 folded in
  const float c2 = c1 / 512.f;
  const float c3 = c2 / 512.f;
  unsigned char* Mb = M8 + Ao;
#pragma unroll
  for (int i = 0; i < 4; ++i) {
    int col = tn * 64 + i * 16 + ln;
#pragma unroll
    for (int r = 0; r < 4; ++r) {
      int row = tm * 64 + w * 16 + q * 4 + r;
      float mval = c1 * A1[Ao + (size_t)row * NN + col] +
                   c2 * bf2f(A2b[(size_t)row * NN + col]) + c3 * acc[i][r];
      Mb[m8_addr(row, col)] = e4m3(mval);
    }
  }
}

// ---------------------------------------------------------------------------
// Slow-path GEMMs (no A1T workspace).
// ---------------------------------------------------------------------------
__global__ __launch_bounds__(256) void gemm_a2_slow(
    const float* __restrict__ A1, unsigned short* __restrict__ A2) {
  const int b = blockIdx.x, tn = blockIdx.y, tm = blockIdx.z;
  const int tid = threadIdx.x, lane = tid & 63, w = tid >> 6;
  const int q = lane >> 4, ln = lane & 15;
  const size_t Ao = (size_t)b * NN * NN;
  f32x4 zero = {0.f, 0.f, 0.f, 0.f};
  f32x4 acc[4] = {zero, zero, zero, zero};
  const float* ap = A1 + Ao + (size_t)(tm * 64 + w * 16 + ln) * NN + q * 8;
  for (int k0 = 0; k0 < NN; k0 += 32) {
    f32x4 x0 = *(const f32x4*)(ap + k0);
    f32x4 x1 = *(const f32x4*)(ap + k0 + 4);
    union { bf16x8 v; unsigned int u[4]; } af;
    af.u[0] = pk_trunc(x0[1], x0[0]);
    af.u[1] = pk_trunc(x0[3], x0[2]);
    af.u[2] = pk_trunc(x1[1], x1[0]);
    af.u[3] = pk_trunc(x1[3], x1[2]);
#pragma unroll
    for (int i = 0; i < 4; ++i) {
      bf16x8 bv;
#pragma unroll
      for (int j = 0; j < 8; ++j)
        bv[j] = (short)f2bf(A1[Ao + (size_t)(k0 + q * 8 + j) * NN + tn * 64 + i * 16 + ln]);
      acc[i] = __builtin_amdgcn_mfma_f32_16x16x32_bf16(af.v, bv, acc[i], 0, 0, 0);
    }
  }
  unsigned short* Cb = A2 + Ao;
#pragma unroll
  for (int i = 0; i < 4; ++i) {
    int col = tn * 64 + i * 16 + ln;
#pragma unroll
    for (int r = 0; r < 4; ++r) {
      int row = tm * 64 + w * 16 + q * 4 + r;
      Cb[(size_t)row * NN + col] = f2bf(acc[i][r]);
    }
  }
}

__global__ __launch_bounds__(256) void gemm_m_slow(
    const float* __restrict__ A1, const unsigned short* __restrict__ A2,
    unsigned char* __restrict__ M8) {
  const int b = blockIdx.x, tn = blockIdx.y, tm = blockIdx.z;
  const int tid = threadIdx.x, lane = tid & 63, w = tid >> 6;
  const int q = lane >> 4, ln = lane & 15;
  const size_t Ao = (size_t)b * NN * NN;
  const unsigned short* A2b = A2 + Ao;
  f32x4 zero = {0.f, 0.f, 0.f, 0.f};
  f32x4 acc[4] = {zero, zero, zero, zero};
  const unsigned short* ap = A2b + (size_t)(tm * 64 + w * 16 + ln) * NN + q * 8;
  for (int k0 = 0; k0 < NN; k0 += 32) {
    bf16x8 af = *(const bf16x8*)(ap + k0);
#pragma unroll
    for (int i = 0; i < 4; ++i) {
      bf16x8 bv;
#pragma unroll
      for (int j = 0; j < 8; ++j)
        bv[j] = (short)f2bf(A1[Ao + (size_t)(k0 + q * 8 + j) * NN + tn * 64 + i * 16 + ln]);
      acc[i] = __builtin_amdgcn_mfma_f32_16x16x32_bf16(af, bv, acc[i], 0, 0, 0);
    }
  }
  const float c1 = 1048576.f / (3.f * 512.f * 512.f);
  const float c2 = c1 / 512.f;
  const float c3 = c2 / 512.f;
  unsigned char* Mb = M8 + Ao;
#pragma unroll
  for (int i = 0; i < 4; ++i) {
    int col = tn * 64 + i * 16 + ln;
#pragma unroll
    for (int r = 0; r < 4; ++r) {
      int row = tm * 64 + w * 16 + q * 4 + r;
      float mval = c1 * A1[Ao + (size_t)row * NN + col] +
                   c2 * bf2f(A2b[(size_t)row * NN + col]) + c3 * acc[i][r];
      Mb[m8_addr(row, col)] = e4m3(mval);
    }
  }
}

// ---------------------------------------------------------------------------
// Scan: 64 blocks x 512 threads, 199 steps. M (fp8, scaled 2^20) lives in 128
// VGPRs/thread; __launch_bounds__(512,2) -> 256-VGPR cap, 1 block/CU, no spill.
// Wave 0 runs the MLP overlapped with the other waves' matvec MFMAs.
// ---------------------------------------------------------------------------
__global__ __launch_bounds__(512, 2) void scan_kernel(
    const int* __restrict__ skills, const int* __restrict__ times,
    const float* __restrict__ labels, const float* __restrict__ emb,
    const float* __restrict__ ub0g, const float* __restrict__ uf0g,
    const float* __restrict__ w1g, const float* __restrict__ b1g,
    const float* __restrict__ w2g, const float* __restrict__ b2g,
    const float* __restrict__ wfg, const float* __restrict__ bfg,
    const float* __restrict__ wbg, const float* __restrict__ bbg,
    const unsigned char* __restrict__ M8, float* __restrict__ out) {
  const int b = blockIdx.x;
  const int t = threadIdx.x;
  const int lane = t & 63, w = t >> 6, q = lane >> 4;

  __shared__ __align__(8) unsigned char lp8[NN];
  __shared__ float ub[DD], uf[DD];
  __shared__ float delta_s[NSTEP], label_s[NSTEP];
  __shared__ int skill_s[NSTEP];
  __shared__ float hp[16][33];
  __shared__ float w1t[DD * 5 * DD];
  __shared__ float w2t[DD * DD], wft[DD * DD], wbt[DD * DD];
  __shared__ float b1s[DD], b2s[DD], bfs[DD], bbs[DD];

  // per-thread node-embedding rows (f32 registers)
  float nrec[DD], nsend[DD];
#pragma unroll
  for (int c = 0; c < DD; ++c) {
    nsend[c] = emb[(size_t)t * (2 * DD) + c];
    nrec[c] = emb[(size_t)t * (2 * DD) + DD + c];
  }
  for (int idx = t; idx < DD * DD * 5; idx += 512) {
    int o = idx / 160, rem = idx % 160;
    w1t[rem * 32 + o] = w1g[idx];
  }
  for (int idx = t; idx < DD * DD; idx += 512) {
    int o = idx >> 5, c = idx & 31;
    w2t[c * 32 + o] = w2g[idx];
    wft[c * 32 + o] = wfg[idx];
    wbt[c * 32 + o] = wbg[idx];
  }
  if (t < DD) {
    b1s[t] = b1g[t]; b2s[t] = b2g[t];
    bfs[t] = bfg[t]; bbs[t] = bbg[t];
    ub[t] = ub0g[b * DD + t];
    uf[t] = uf0g[b * DD + t];
  }
  for (int i = t; i < NSTEP; i += 512) {
    int dt_ = times[b * TTOT + i + 1] - times[b * TTOT + i];
    if (dt_ < 0) dt_ = -dt_;
    delta_s[i] = __logf((float)dt_ + 1e-6f) * 0.6213349345596119f;  // 1/ln 5
    label_s[i] = labels[b * TTOT + i + 1];
    skill_s[i] = skills[b * TTOT + i + 1];
  }

  // preload step-invariant M fragments: 64 x i64 = 128 VGPRs
  const unsigned char* Mb = M8 + (size_t)b * NN * NN;
  long mreg[64];
#pragma unroll
  for (int c = 0; c < 16; ++c)
#pragma unroll
    for (int i = 0; i < 4; ++i)
      mreg[c * 4 + i] =
          *(const long*)(Mb + (((size_t)(w * 64 + i * 16 + c)) << 9) + (size_t)lane * 8);
  __syncthreads();

  // initial last_perf / node_last_forget (f32, thread-private registers)
  float rlp = 0.f, rnlf = 0.f;
#pragma unroll
  for (int c = 0; c < DD; ++c) {
    rlp += ub[c] * nrec[c];
    rnlf += uf[c] * nsend[c];
  }
  lp8[t] = e4m3(rlp);
  __syncthreads();

  for (int step = 0; step < NSTEP; ++step) {
    // ---- Phase A: wave0 MLP (ub/uf update) overlapped with matvec MFMAs ----
    if (step && w == 0) {
      int o = lane & 31, half = lane >> 5;
      float part = 0.f;
#pragma unroll
      for (int s2 = 0; s2 < 8; ++s2) part += hp[half * 8 + s2][o];
      float h = b1s[o] + part + __shfl_xor(part, 32);
      h = fmaxf(h, 0.f);
      float up = 0.f;
#pragma unroll
      for (int cc = 0; cc < 16; ++cc) {
        float hv0 = rlane(h, cc), hv1 = rlane(h, 16 + cc);
        up += (half ? hv1 : hv0) * w2t[(half * 16 + cc) * 32 + o];
      }
      float uu = b2s[o] + up + __shfl_xor(up, 32);
      const float* wsel = half ? wbt : wft;
      float aac = half ? bbs[o] : bfs[o];
#pragma unroll
      for (int c = 0; c < DD; ++c) aac += rlane(uu, c) * wsel[c * 32 + o];
      float val = 1.f - 2.f / (1.f + __expf(2.f * aac));
      if (half) ub[o] = val;  // new_b -> user_b
      else uf[o] = val;       // new_f -> user_f
    }
    f32x4 zero = {0.f, 0.f, 0.f, 0.f};
    f32x4 acc[4] = {zero, zero, zero, zero};
#pragma unroll
    for (int c = 0; c < 16; ++c) {
      long af = *(const long*)(lp8 + c * 32 + q * 8);
#pragma unroll
      for (int i = 0; i < 4; ++i)
        acc[i] = __builtin_amdgcn_mfma_f32_16x16x32_fp8_fp8(af, mreg[c * 4 + i],
                                                            acc[i], 0, 0, 0);
    }
    float spatial = ((q == 0) ? acc[0][0]
                   : (q == 1) ? acc[1][0]
                   : (q == 2) ? acc[2][0] : acc[3][0]) * 0x1p-20f;
    __syncthreads();  // sync1: ub/uf updated; all matvec reads of lp8 done

    // ---- Phase B ----
    float rub = ub[lane & 31], ruf = uf[lane & 31];
    float n0 = 0.f, n1 = 0.f, n2 = 0.f, n3 = 0.f;
    float l0 = 0.f, l1 = 0.f, l2 = 0.f, l3 = 0.f;
#pragma unroll
    for (int c = 0; c < 8; ++c) {
      n0 += rlane(rub, c) * nrec[c];
      n1 += rlane(rub, 8 + c) * nrec[8 + c];
      n2 += rlane(rub, 16 + c) * nrec[16 + c];
      n3 += rlane(rub, 24 + c) * nrec[24 + c];
      l0 += rlane(ruf, c) * nsend[c];
      l1 += rlane(ruf, 8 + c) * nsend[8 + c];
      l2 += rlane(ruf, 16 + c) * nsend[16 + c];
      l3 += rlane(ruf, 24 + c) * nsend[24 + c];
    }
    float ncb = (n0 + n1) + (n2 + n3);
    float nlfn = (l0 + l1) + (l2 + l3);
    float e = __expf(-delta_s[step] * 0.1f * rnlf) * rlp;
    float cur = 1.f / (1.f + __expf(-(ncb + e + spatial)));

    {  // MLP h partials: all 512 threads (o = t&31, c-slice = t>>5)
      int o = t & 31, s = t >> 5;
      float lab = label_s[step];
      int sk = skill_s[step];
      float hpart = 0.f;
#pragma unroll
      for (int cc = 0; cc < 2; ++cc) {
        int c = (s << 1) + cc;
        const float* wrow = &w1t[(c * 5) * 32 + o];
        float rs = emb[(size_t)sk * (2 * DD) + c];       // node_send[sk][c]
        float rr = emb[(size_t)sk * (2 * DD) + DD + c];  // node_rec[sk][c]
        hpart += ub[c] * wrow[0] + uf[c] * wrow[32] + lab * wrow[64] +
                 rr * wrow[96] + rs * wrow[128];
      }
      hp[s][o] = hpart;
    }

    rlp = cur;
    rnlf = nlfn;
    lp8[t] = e4m3(cur);
    if (t == skill_s[step]) out[step * BSZ + b] = cur;
    __syncthreads();  // sync2: lp8/hp ready for next step
  }
}

extern "C" void kernel_launch(void* const* d_in, const int* in_sizes, int n_in,
                              void* d_out, int out_size, void* d_ws, size_t ws_size,
                              hipStream_t stream) {
  (void)in_sizes; (void)n_in; (void)out_size;
  const int* skills = (const int*)d_in[0];
  const int* times = (const int*)d_in[1];
  const float* labels = (const float*)d_in[2];
  const float* adj = (const float*)d_in[3];
  const float* emb = (const float*)d_in[4];

  const size_t mat = (size_t)BSZ * NN * NN;
  unsigned char* M8 = (unsigned char*)d_ws + 256;                    // 16.8 MB
  unsigned short* A2 = (unsigned short*)(M8 + mat);                  // 33.5 MB
  unsigned short* A1T = (unsigned short*)((char*)A2 + mat * 2);      // 33.5 MB
  size_t need_fast = 256 + mat + 4 * mat;

  dim3 gg(BSZ, 8, 8), gb(256);
  if (ws_size >= need_fast) {
    transpose_kernel<<<gg, gb, 0, stream>>>(adj, A1T);
    gemm_a2_fast<<<gg, gb, 0, stream>>>(adj, A1T, A2);
    gemm_m_fast<<<gg, gb, 0, stream>>>(adj, A1T, A2, M8);
  } else {
    gemm_a2_slow<<<gg, gb, 0, stream>>>(adj, A2);
    gemm_m_slow<<<gg, gb, 0, stream>>>(adj, A2, M8);
  }
  scan_kernel<<<dim3(BSZ), dim3(512), 0, stream>>>(
      skills, times, labels, emb, (const float*)d_in[5], (const float*)d_in[6],
      (const float*)d_in[7], (const float*)d_in[8], (const float*)d_in[9],
      (const float*)d_in[10], (const float*)d_in[11], (const float*)d_in[12],
      (const float*)d_in[13], (const float*)d_in[14], M8, (float*)d_out);
}

// Round 7
// 883.329 us; speedup vs baseline: 2.9272x; 1.0181x over previous
//
#include <hip/hip_runtime.h>

#define NN 512
#define BSZ 64
#define TTOT 200
#define NSTEP 199
#define DD 32

typedef __attribute__((ext_vector_type(8))) short bf16x8;
typedef __attribute__((ext_vector_type(8))) int i32x8;
typedef __attribute__((ext_vector_type(4))) float f32x4;
typedef __attribute__((ext_vector_type(4))) unsigned int u32x4;

__device__ __forceinline__ float bf2f(unsigned short u) {
  union { unsigned int i; float f; } v; v.i = ((unsigned int)u) << 16; return v.f;
}
__device__ __forceinline__ unsigned short f2bf(float f) {  // RNE
  unsigned int b = __float_as_uint(f);
  return (unsigned short)((b + 0x7fffu + ((b >> 16) & 1u)) >> 16);
}
__device__ __forceinline__ unsigned int pk_trunc(float hi, float lo) {
  return __builtin_amdgcn_perm(__float_as_uint(hi), __float_as_uint(lo), 0x07060302u);
}
// f32 -> OCP e4m3 (RNE on normals; flush tiny to 0; clamp 448)
__device__ __forceinline__ unsigned char e4m3(float x) {
  float a = fabsf(x);
  unsigned int s = (__float_as_uint(x) >> 24) & 0x80u;
  if (a < 0.01171875f) return (unsigned char)s;
  a = fminf(a, 448.0f);
  unsigned int u = __float_as_uint(a);
  unsigned int keep = (u >> 20) & 7u;
  unsigned int rest = u & 0xFFFFFu;
  unsigned int base = (((u >> 23) - 120u) << 3) | keep;
  unsigned int rnd = (rest > 0x80000u) || (rest == 0x80000u && (keep & 1u));
  return (unsigned char)(s | (base + rnd));
}
__device__ __forceinline__ float dec8(unsigned char x) {  // e4m3 -> f32
  int e = (x >> 3) & 15, m = x & 7;
  float v = e ? ldexpf(8.f + (float)m, e - 10) : ldexpf((float)m, -9);
  return (x & 0x80) ? -v : v;
}
__device__ __forceinline__ float rlane(float v, int l) {
  return __int_as_float(__builtin_amdgcn_readlane(__float_as_int(v), l));
}

// K=32 fp8 B-frag layout (round-4 HW-PROVEN)
__device__ __forceinline__ size_t m8_addr(int k, int col) {
  int nt = col >> 4, cch = k >> 5;
  int l2 = (((k >> 3) & 3) << 4) + (col & 15);
  return (size_t)((nt * 16 + cch) * 512) + (size_t)l2 * 8 + (size_t)(k & 7);
}
// K=128 MX B-frag layout (assumed -> runtime probe-verified)
__device__ __forceinline__ size_t m8mxa(int k, int col) {
  int f = ((k >> 7) << 5) + (col >> 4);
  int ln2 = (((k >> 5) & 3) << 4) + (col & 15);
  return (((size_t)f * 64 + ln2) << 5) + (size_t)(k & 31);
}

// ---------------------------------------------------------------------------
// Transpose+convert: A1 (f32 [b][r][c]) -> A1T (bf16 [b][c][r]).  [round 4]
// ---------------------------------------------------------------------------
__global__ __launch_bounds__(256) void transpose_kernel(
    const float* __restrict__ A1, unsigned short* __restrict__ A1T) {
  const int b = blockIdx.x, ct = blockIdx.y * 64, rt = blockIdx.z * 64;
  const int t = threadIdx.x;
  __shared__ unsigned int tl[64][33];
  {
    const int rp = t >> 3, cs = (t & 7) * 8;
    const float* p0 = A1 + (size_t)b * NN * NN + (size_t)(rt + 2 * rp) * NN + ct + cs;
    f32x4 a0 = *(const f32x4*)p0, a1 = *(const f32x4*)(p0 + 4);
    f32x4 b0 = *(const f32x4*)(p0 + NN), b1 = *(const f32x4*)(p0 + NN + 4);
#pragma unroll
    for (int j = 0; j < 4; ++j) {
      tl[cs + j][rp] = pk_trunc(b0[j], a0[j]);
      tl[cs + 4 + j][rp] = pk_trunc(b1[j], a1[j]);
    }
  }
  __syncthreads();
  {
    const int c = t >> 2, rps = (t & 3) * 8;
    unsigned int v[8];
#pragma unroll
    for (int j = 0; j < 8; ++j) v[j] = tl[c][rps + j];
    unsigned int* dst = (unsigned int*)(A1T + (size_t)b * NN * NN +
                                        (size_t)(ct + c) * NN + rt) + rps;
    *(u32x4*)dst = u32x4{v[0], v[1], v[2], v[3]};
    *(u32x4*)(dst + 4) = u32x4{v[4], v[5], v[6], v[7]};
  }
}

// ---------------------------------------------------------------------------
// GEMM 1 fast: A2 = A1@A1 bf16 out.  [round 4]
// ---------------------------------------------------------------------------
__global__ __launch_bounds__(256) void gemm_a2_fast(
    const float* __restrict__ A1, const unsigned short* __restrict__ A1T,
    unsigned short* __restrict__ A2) {
  const int b = blockIdx.x, tn = blockIdx.y, tm = blockIdx.z;
  const int tid = threadIdx.x, lane = tid & 63, w = tid >> 6;
  const int q = lane >> 4, ln = lane & 15;
  const size_t Ao = (size_t)b * NN * NN;
  f32x4 zero = {0.f, 0.f, 0.f, 0.f};
  f32x4 acc[4] = {zero, zero, zero, zero};
  const float* ap = A1 + Ao + (size_t)(tm * 64 + w * 16 + ln) * NN + q * 8;
  const unsigned short* bt = A1T + Ao;
  for (int k0 = 0; k0 < NN; k0 += 32) {
    f32x4 x0 = *(const f32x4*)(ap + k0);
    f32x4 x1 = *(const f32x4*)(ap + k0 + 4);
    union { bf16x8 v; unsigned int u[4]; } af;
    af.u[0] = pk_trunc(x0[1], x0[0]);
    af.u[1] = pk_trunc(x0[3], x0[2]);
    af.u[2] = pk_trunc(x1[1], x1[0]);
    af.u[3] = pk_trunc(x1[3], x1[2]);
#pragma unroll
    for (int i = 0; i < 4; ++i) {
      bf16x8 bv = *(const bf16x8*)(bt + (size_t)(tn * 64 + i * 16 + ln) * NN + k0 + q * 8);
      acc[i] = __builtin_amdgcn_mfma_f32_16x16x32_bf16(af.v, bv, acc[i], 0, 0, 0);
    }
  }
  unsigned short* Cb = A2 + Ao;
#pragma unroll
  for (int i = 0; i < 4; ++i) {
    int col = tn * 64 + i * 16 + ln;
#pragma unroll
    for (int r = 0; r < 4; ++r) {
      int row = tm * 64 + w * 16 + q * 4 + r;
      Cb[(size_t)row * NN + col] = f2bf(acc[i][r]);
    }
  }
}

// ---------------------------------------------------------------------------
// GEMM 2 fast: A3 = A2@A1; M*2^20 -> e4m3, dual-written K32 (+MX if enabled).
// ---------------------------------------------------------------------------
__global__ __launch_bounds__(256) void gemm_m_fast(
    const float* __restrict__ A1, const unsigned short* __restrict__ A1T,
    const unsigned short* __restrict__ A2, unsigned char* __restrict__ M8k,
    unsigned char* __restrict__ M8x, int has_mx) {
  const int b = blockIdx.x, tn = blockIdx.y, tm = blockIdx.z;
  const int tid = threadIdx.x, lane = tid & 63, w = tid >> 6;
  const int q = lane >> 4, ln = lane & 15;
  const size_t Ao = (size_t)b * NN * NN;
  const unsigned short* A2b = A2 + Ao;
  f32x4 zero = {0.f, 0.f, 0.f, 0.f};
  f32x4 acc[4] = {zero, zero, zero, zero};
  const unsigned short* ap = A2b + (size_t)(tm * 64 + w * 16 + ln) * NN + q * 8;
  const unsigned short* bt = A1T + Ao;
  for (int k0 = 0; k0 < NN; k0 += 32) {
    bf16x8 af = *(const bf16x8*)(ap + k0);
#pragma unroll
    for (int i = 0; i < 4; ++i) {
      bf16x8 bv = *(const bf16x8*)(bt + (size_t)(tn * 64 + i * 16 + ln) * NN + k0 + q * 8);
      acc[i] = __builtin_amdgcn_mfma_f32_16x16x32_bf16(af, bv, acc[i], 0, 0, 0);
    }
  }
  const float c1 = 1048576.f / (3.f * 512.f * 512.f);
  const float c2 = c1 / 512.f;
  const float c3 = c2 / 512.f;
  unsigned char* Mk = M8k + Ao;
  unsigned char* Mx = M8x + Ao;
#pragma unroll
  for (int i = 0; i < 4; ++i) {
    int col = tn * 64 + i * 16 + ln;
#pragma unroll
    for (int r = 0; r < 4; ++r) {
      int row = tm * 64 + w * 16 + q * 4 + r;
      float mval = c1 * A1[Ao + (size_t)row * NN + col] +
                   c2 * bf2f(A2b[(size_t)row * NN + col]) + c3 * acc[i][r];
      unsigned char mb = e4m3(mval);
      Mk[m8_addr(row, col)] = mb;
      if (has_mx) Mx[m8mxa(row, col)] = mb;
    }
  }
}

// ---------------------------------------------------------------------------
// Slow GEMMs (round-2/4 proven; scalar b-frag f2bf loads).
// ---------------------------------------------------------------------------
__global__ __launch_bounds__(256) void gemm_a2_slow(
    const float* __restrict__ A1, unsigned short* __restrict__ A2) {
  const int b = blockIdx.x, tn = blockIdx.y, tm = blockIdx.z;
  const int tid = threadIdx.x, lane = tid & 63, w = tid >> 6;
  const int q = lane >> 4, ln = lane & 15;
  const size_t Ao = (size_t)b * NN * NN;
  f32x4 zero = {0.f, 0.f, 0.f, 0.f};
  f32x4 acc[4] = {zero, zero, zero, zero};
  const float* ap = A1 + Ao + (size_t)(tm * 64 + w * 16 + ln) * NN + q * 8;
  for (int k0 = 0; k0 < NN; k0 += 32) {
    f32x4 x0 = *(const f32x4*)(ap + k0);
    f32x4 x1 = *(const f32x4*)(ap + k0 + 4);
    union { bf16x8 v; unsigned int u[4]; } af;
    af.u[0] = pk_trunc(x0[1], x0[0]);
    af.u[1] = pk_trunc(x0[3], x0[2]);
    af.u[2] = pk_trunc(x1[1], x1[0]);
    af.u[3] = pk_trunc(x1[3], x1[2]);
#pragma unroll
    for (int i = 0; i < 4; ++i) {
      bf16x8 bv;
#pragma unroll
      for (int j = 0; j < 8; ++j)
        bv[j] = (short)f2bf(A1[Ao + (size_t)(k0 + q * 8 + j) * NN + tn * 64 + i * 16 + ln]);
      acc[i] = __builtin_amdgcn_mfma_f32_16x16x32_bf16(af.v, bv, acc[i], 0, 0, 0);
    }
  }
  unsigned short* Cb = A2 + Ao;
#pragma unroll
  for (int i = 0; i < 4; ++i) {
    int col = tn * 64 + i * 16 + ln;
#pragma unroll
    for (int r = 0; r < 4; ++r) {
      int row = tm * 64 + w * 16 + q * 4 + r;
      Cb[(size_t)row * NN + col] = f2bf(acc[i][r]);
    }
  }
}

__global__ __launch_bounds__(256) void gemm_m_slow(
    const float* __restrict__ A1, const unsigned short* __restrict__ A2,
    unsigned char* __restrict__ M8k, unsigned char* __restrict__ M8x,
    int has_mx) {
  const int b = blockIdx.x, tn = blockIdx.y, tm = blockIdx.z;
  const int tid = threadIdx.x, lane = tid & 63, w = tid >> 6;
  const int q = lane >> 4, ln = lane & 15;
  const size_t Ao = (size_t)b * NN * NN;
  const unsigned short* A2b = A2 + Ao;
  f32x4 zero = {0.f, 0.f, 0.f, 0.f};
  f32x4 acc[4] = {zero, zero, zero, zero};
  const unsigned short* ap = A2b + (size_t)(tm * 64 + w * 16 + ln) * NN + q * 8;
  for (int k0 = 0; k0 < NN; k0 += 32) {
    bf16x8 af = *(const bf16x8*)(ap + k0);
#pragma unroll
    for (int i = 0; i < 4; ++i) {
      bf16x8 bv;
#pragma unroll
      for (int j = 0; j < 8; ++j)
        bv[j] = (short)f2bf(A1[Ao + (size_t)(k0 + q * 8 + j) * NN + tn * 64 + i * 16 + ln]);
      acc[i] = __builtin_amdgcn_mfma_f32_16x16x32_bf16(af, bv, acc[i], 0, 0, 0);
    }
  }
  const float c1 = 1048576.f / (3.f * 512.f * 512.f);
  const float c2 = c1 / 512.f;
  const float c3 = c2 / 512.f;
  unsigned char* Mk = M8k + Ao;
  unsigned char* Mx = M8x + Ao;
#pragma unroll
  for (int i = 0; i < 4; ++i) {
    int col = tn * 64 + i * 16 + ln;
#pragma unroll
    for (int r = 0; r < 4; ++r) {
      int row = tm * 64 + w * 16 + q * 4 + r;
      float mval = c1 * A1[Ao + (size_t)row * NN + col] +
                   c2 * bf2f(A2b[(size_t)row * NN + col]) + c3 * acc[i][r];
      unsigned char mb = e4m3(mval);
      Mk[m8_addr(row, col)] = mb;
      if (has_mx) Mx[m8mxa(row, col)] = mb;
    }
  }
}

// ---------------------------------------------------------------------------
// Probe: HW-verify the assumed K=128 MX layout + scale semantics.
// ---------------------------------------------------------------------------
__global__ __launch_bounds__(64) void probe_kernel(int* __restrict__ flag) {
  const int lane = threadIdx.x, q = lane >> 4, n = lane & 15;
  __shared__ unsigned char A8[128];
  __shared__ unsigned char B8[128 * 16];
  for (int k = lane; k < 128; k += 64) A8[k] = (unsigned char)(8 + ((k * 37 + 11) % 56));
  for (int i = lane; i < 2048; i += 64)
    B8[i] = (unsigned char)(((i & 1) ? 0x80 : 0) | (8 + ((i * 23 + 5) % 56)));
  __syncthreads();
  union { i32x8 v; unsigned char b[32]; } af, bf;
#pragma unroll
  for (int j = 0; j < 32; ++j) {
    af.b[j] = A8[q * 32 + j];
    bf.b[j] = B8[(q * 32 + j) * 16 + n];
  }
  f32x4 acc = {0.f, 0.f, 0.f, 0.f};
  acc = __builtin_amdgcn_mfma_scale_f32_16x16x128_f8f6f4(af.v, bf.v, acc, 0, 0,
                                                         0, 127, 0, 127);
  float ref = 0.f;
  for (int k = 0; k < 128; ++k) ref += dec8(A8[k]) * dec8(B8[k * 16 + n]);
  int ok = 1;
#pragma unroll
  for (int r = 0; r < 4; ++r)
    ok &= (fabsf(acc[r] - ref) <= 1e-3f * fmaxf(fabsf(ref), 1.f)) ? 1 : 0;
  unsigned long long bal = __ballot(ok);
  if (lane == 0) *flag = (bal == ~0ull) ? 1 : 0;
}

// ---------------------------------------------------------------------------
// Scan: ROUND-4 STRUCTURE VERBATIM (proven at absmax 2e-3). Only the matvec
// switches between probe-verified MX K=128 and the proven K=32 fp8 path.
// ---------------------------------------------------------------------------
__global__ __launch_bounds__(512, 2) void scan_kernel(
    const int* __restrict__ skills, const int* __restrict__ times,
    const float* __restrict__ labels, const float* __restrict__ emb,
    const float* __restrict__ ub0g, const float* __restrict__ uf0g,
    const float* __restrict__ w1g, const float* __restrict__ b1g,
    const float* __restrict__ w2g, const float* __restrict__ b2g,
    const float* __restrict__ wfg, const float* __restrict__ bfg,
    const float* __restrict__ wbg, const float* __restrict__ bbg,
    const unsigned char* __restrict__ M8k, const unsigned char* __restrict__ M8x,
    int allow_mx, const int* __restrict__ flag, float* __restrict__ out) {
  const int b = blockIdx.x;
  const int t = threadIdx.x;
  const int lane = t & 63, w = t >> 6, q = lane >> 4;

  __shared__ __align__(32) unsigned char lp8[NN];
  __shared__ float ub[DD], uf[DD];
  __shared__ float delta_s[NSTEP], label_s[NSTEP];
  __shared__ int skill_s[NSTEP];
  __shared__ float hp[16][33];
  __shared__ float w1t[DD * 5 * DD];
  __shared__ float w2t[DD * DD], wft[DD * DD], wbt[DD * DD];
  __shared__ float b1s[DD], b2s[DD], bfs[DD], bbs[DD];

  const int use_mx = allow_mx && (*flag);

  float nrec[DD], nsend[DD];
#pragma unroll
  for (int c = 0; c < DD; ++c) {
    nsend[c] = emb[(size_t)t * (2 * DD) + c];
    nrec[c] = emb[(size_t)t * (2 * DD) + DD + c];
  }
  for (int idx = t; idx < DD * DD * 5; idx += 512) {
    int o = idx / 160, rem = idx % 160;
    w1t[rem * 32 + o] = w1g[idx];
  }
  for (int idx = t; idx < DD * DD; idx += 512) {
    int o = idx >> 5, c = idx & 31;
    w2t[c * 32 + o] = w2g[idx];
    wft[c * 32 + o] = wfg[idx];
    wbt[c * 32 + o] = wbg[idx];
  }
  if (t < DD) {
    b1s[t] = b1g[t]; b2s[t] = b2g[t];
    bfs[t] = bfg[t]; bbs[t] = bbg[t];
    ub[t] = ub0g[b * DD + t];
    uf[t] = uf0g[b * DD + t];
  }
  for (int i = t; i < NSTEP; i += 512) {
    int dt_ = times[b * TTOT + i + 1] - times[b * TTOT + i];
    if (dt_ < 0) dt_ = -dt_;
    delta_s[i] = __logf((float)dt_ + 1e-6f) * 0.6213349345596119f;  // 1/ln 5
    label_s[i] = labels[b * TTOT + i + 1];
    skill_s[i] = skills[b * TTOT + i + 1];
  }

  // preload step-invariant M fragments: 128 VGPRs either path
  union MU { i32x8 v; long l[4]; };
  MU mreg[16];
  if (use_mx) {
    const unsigned char* Mb = M8x + (size_t)b * NN * NN;
#pragma unroll
    for (int c = 0; c < 4; ++c)
#pragma unroll
      for (int i = 0; i < 4; ++i)
        mreg[c * 4 + i].v = *(const i32x8*)(
            Mb + (((size_t)(c * 32 + w * 4 + i) * 64 + lane) << 5));
  } else {
    const unsigned char* Mb = M8k + (size_t)b * NN * NN;
#pragma unroll
    for (int c = 0; c < 16; ++c)
#pragma unroll
      for (int i = 0; i < 4; ++i)
        mreg[c].l[i] = *(const long*)(
            Mb + (((size_t)(w * 64 + i * 16 + c)) << 9) + (size_t)lane * 8);
  }
  __syncthreads();

  float rlp = 0.f, rnlf = 0.f;
#pragma unroll
  for (int c = 0; c < DD; ++c) {
    rlp += ub[c] * nrec[c];
    rnlf += uf[c] * nsend[c];
  }
  lp8[t] = e4m3(rlp);
  __syncthreads();

  for (int step = 0; step < NSTEP; ++step) {
    // ---- Phase A: wave0 MLP overlapped with matvec MFMAs ----
    if (step && w == 0) {
      int o = lane & 31, half = lane >> 5;
      float part = 0.f;
#pragma unroll
      for (int s2 = 0; s2 < 8; ++s2) part += hp[half * 8 + s2][o];
      float h = b1s[o] + part + __shfl_xor(part, 32);
      h = fmaxf(h, 0.f);
      float up = 0.f;
#pragma unroll
      for (int cc = 0; cc < 16; ++cc) {
        float hv0 = rlane(h, cc), hv1 = rlane(h, 16 + cc);
        up += (half ? hv1 : hv0) * w2t[(half * 16 + cc) * 32 + o];
      }
      float uu = b2s[o] + up + __shfl_xor(up, 32);
      const float* wsel = half ? wbt : wft;
      float aac = half ? bbs[o] : bfs[o];
#pragma unroll
      for (int c = 0; c < DD; ++c) aac += rlane(uu, c) * wsel[c * 32 + o];
      float val = 1.f - 2.f / (1.f + __expf(2.f * aac));
      if (half) ub[o] = val;
      else uf[o] = val;
    }
    f32x4 zero = {0.f, 0.f, 0.f, 0.f};
    f32x4 acc[4] = {zero, zero, zero, zero};
    if (use_mx) {
#pragma unroll
      for (int c = 0; c < 4; ++c) {
        i32x8 af = *(const i32x8*)(&lp8[c * 128 + q * 32]);
#pragma unroll
        for (int i = 0; i < 4; ++i)
          acc[i] = __builtin_amdgcn_mfma_scale_f32_16x16x128_f8f6f4(
              af, mreg[c * 4 + i].v, acc[i], 0, 0, 0, 127, 0, 127);
      }
    } else {
#pragma unroll
      for (int c = 0; c < 16; ++c) {
        long af = *(const long*)(&lp8[c * 32 + q * 8]);
#pragma unroll
        for (int i = 0; i < 4; ++i)
          acc[i] = __builtin_amdgcn_mfma_f32_16x16x32_fp8_fp8(af, mreg[c].l[i],
                                                              acc[i], 0, 0, 0);
      }
    }
    float spatial = ((q & 2) ? ((q & 1) ? acc[3][0] : acc[2][0])
                             : ((q & 1) ? acc[1][0] : acc[0][0])) * 0x1p-20f;
    __syncthreads();  // sync1: ub/uf updated; all matvec reads of lp8 done

    // ---- Phase B ----
    float rub = ub[lane & 31], ruf = uf[lane & 31];
    float n0 = 0.f, n1 = 0.f, n2 = 0.f, n3 = 0.f;
    float l0 = 0.f, l1 = 0.f, l2 = 0.f, l3 = 0.f;
#pragma unroll
    for (int c = 0; c < 8; ++c) {
      n0 += rlane(rub, c) * nrec[c];
      n1 += rlane(rub, 8 + c) * nrec[8 + c];
      n2 += rlane(rub, 16 + c) * nrec[16 + c];
      n3 += rlane(rub, 24 + c) * nrec[24 + c];
      l0 += rlane(ruf, c) * nsend[c];
      l1 += rlane(ruf, 8 + c) * nsend[8 + c];
      l2 += rlane(ruf, 16 + c) * nsend[16 + c];
      l3 += rlane(ruf, 24 + c) * nsend[24 + c];
    }
    float ncb = (n0 + n1) + (n2 + n3);
    float nlfn = (l0 + l1) + (l2 + l3);
    float e = __expf(-delta_s[step] * 0.1f * rnlf) * rlp;
    float cur = 1.f / (1.f + __expf(-(ncb + e + spatial)));

    {
      int o = t & 31, s = t >> 5;
      float lab = label_s[step];
      int sk = skill_s[step];
      float hpart = 0.f;
#pragma unroll
      for (int cc = 0; cc < 2; ++cc) {
        int c = (s << 1) + cc;
        const float* wrow = &w1t[(c * 5) * 32 + o];
        float rs = emb[(size_t)sk * (2 * DD) + c];
        float rr = emb[(size_t)sk * (2 * DD) + DD + c];
        hpart += ub[c] * wrow[0] + uf[c] * wrow[32] + lab * wrow[64] +
                 rr * wrow[96] + rs * wrow[128];
      }
      hp[s][o] = hpart;
    }

    rlp = cur;
    rnlf = nlfn;
    lp8[t] = e4m3(cur);
    if (t == skill_s[step]) out[step * BSZ + b] = cur;
    __syncthreads();  // sync2: lp8/hp ready for next step
  }
}

extern "C" void kernel_launch(void* const* d_in, const int* in_sizes, int n_in,
                              void* d_out, int out_size, void* d_ws, size_t ws_size,
                              hipStream_t stream) {
  (void)in_sizes; (void)n_in; (void)out_size;
  const int* skills = (const int*)d_in[0];
  const int* times = (const int*)d_in[1];
  const float* labels = (const float*)d_in[2];
  const float* adj = (const float*)d_in[3];
  const float* emb = (const float*)d_in[4];

  const size_t mat = (size_t)BSZ * NN * NN;  // 16,777,216 B per fp8 matrix
  char* base = (char*)d_ws;
  unsigned char *M8k, *M8x;
  unsigned short *A2, *A1T = nullptr;
  int* flag;
  int use_fast, allow_mx;
  if (ws_size >= 6 * mat + 4) {          // 100,663,300: fast gemms + MX
    use_fast = 1; allow_mx = 1;
    M8k = (unsigned char*)base; M8x = M8k + mat;
    A2 = (unsigned short*)(base + 2 * mat);
    A1T = (unsigned short*)(base + 4 * mat);
    flag = (int*)(base + 6 * mat);
  } else if (ws_size >= 5 * mat + 4) {   // 83,886,084: fast gemms, no MX
    use_fast = 1; allow_mx = 0;
    M8k = (unsigned char*)base; M8x = M8k;
    A2 = (unsigned short*)(base + mat);
    A1T = (unsigned short*)(base + 3 * mat);
    flag = (int*)(base + 5 * mat);
  } else if (ws_size >= 4 * mat + 4) {   // 67,108,868: slow gemms + MX (proven floor)
    use_fast = 0; allow_mx = 1;
    M8k = (unsigned char*)base; M8x = M8k + mat;
    A2 = (unsigned short*)(base + 2 * mat);
    flag = (int*)(base + 4 * mat);
  } else {                               // slow, no MX
    use_fast = 0; allow_mx = 0;
    M8k = (unsigned char*)base; M8x = M8k;
    A2 = (unsigned short*)(base + mat);
    flag = (int*)(base + 3 * mat);
  }

  dim3 gg(BSZ, 8, 8), gb(256);
  if (use_fast) {
    transpose_kernel<<<gg, gb, 0, stream>>>(adj, A1T);
    gemm_a2_fast<<<gg, gb, 0, stream>>>(adj, A1T, A2);
    gemm_m_fast<<<gg, gb, 0, stream>>>(adj, A1T, A2, M8k, M8x, allow_mx);
  } else {
    gemm_a2_slow<<<gg, gb, 0, stream>>>(adj, A2);
    gemm_m_slow<<<gg, gb, 0, stream>>>(adj, A2, M8k, M8x, allow_mx);
  }
  probe_kernel<<<dim3(1), dim3(64), 0, stream>>>(flag);
  scan_kernel<<<dim3(BSZ), dim3(512), 0, stream>>>(
      skills, times, labels, emb, (const float*)d_in[5], (const float*)d_in[6],
      (const float*)d_in[7], (const float*)d_in[8], (const float*)d_in[9],
      (const float*)d_in[10], (const float*)d_in[11], (const float*)d_in[12],
      (const float*)d_in[13], (const float*)d_in[14], M8k, M8x, allow_mx, flag,
      (float*)d_out);
}